// Round 3
// baseline (839.430 us; speedup 1.0000x reference)
//
#include <hip/hip_runtime.h>

#define N_NODES 50000
#define N_EDGES 800000

typedef __attribute__((ext_vector_type(8))) short short8;
typedef __attribute__((ext_vector_type(4))) float f32x4;

// float -> bf16 (round-to-nearest-even), bit pattern in a short.
__device__ __forceinline__ short bf16_rne(float f) {
  unsigned u = __float_as_uint(f);
  unsigned r = (u + 0x7FFFu + ((u >> 16) & 1u)) >> 16;
  return (short)r;
}

// ---------------------------------------------------------------------------
// Kernel A: per-node projections. NP row layout (reordered for gather locality):
//   NP[n][0:64]    = P_ad = n_feat[n] @ Wa_d     (dst window starts here)
//   NP[n][64:128]  = P_e  = n_feat[n] @ W_e      (shared by src+dst windows)
//   NP[n][128:192] = P_as = n_feat[n] @ Wa_s     (src window)
//   NP[n][192:256] = P_ts = n_feat[n] @ Wt_s     (src window)
//   NP[n][256:320] = P_td = n_feat[n] @ Wt_d     (only read by node_final)
// dst gathers cols [0,128); src gathers cols [64,256) -- both contiguous.
// ---------------------------------------------------------------------------
__global__ __launch_bounds__(64) void node_proj(
    const float* __restrict__ n_feat, const float* __restrict__ W_a,
    const float* __restrict__ W_T, const float* __restrict__ W_e,
    float* __restrict__ NP) {
  __shared__ float sN[16 * 128];
  const int lane = threadIdx.x;
  const int n0 = blockIdx.x * 16;

  float4* sN4 = (float4*)sN;
  const float4* nf4 = (const float4*)(n_feat + (size_t)n0 * 128);
  #pragma unroll
  for (int t = 0; t < 8; ++t) sN4[t * 64 + lane] = nf4[t * 64 + lane];
  __syncthreads();

  float acc[5][16];
  #pragma unroll
  for (int q = 0; q < 5; ++q)
    #pragma unroll
    for (int i = 0; i < 16; ++i) acc[q][i] = 0.f;

  for (int k = 0; k < 128; ++k) {
    float w0 = W_a[k * 64 + lane];          // Wa_d
    float w1 = W_a[(192 + k) * 64 + lane];  // Wa_s
    float w2 = W_T[k * 64 + lane];          // Wt_d
    float w3 = W_T[(192 + k) * 64 + lane];  // Wt_s
    float w4 = W_e[k * 64 + lane];          // W_e
    #pragma unroll
    for (int i = 0; i < 16; ++i) {
      float nv = sN[i * 128 + k];
      acc[0][i] = __builtin_fmaf(nv, w0, acc[0][i]);
      acc[1][i] = __builtin_fmaf(nv, w1, acc[1][i]);
      acc[2][i] = __builtin_fmaf(nv, w2, acc[2][i]);
      acc[3][i] = __builtin_fmaf(nv, w3, acc[3][i]);
      acc[4][i] = __builtin_fmaf(nv, w4, acc[4][i]);
    }
  }
  #pragma unroll
  for (int i = 0; i < 16; ++i) {
    size_t base = (size_t)(n0 + i) * 320;
    NP[base +   0 + lane] = acc[0][i];  // P_ad
    NP[base +  64 + lane] = acc[4][i];  // P_e
    NP[base + 128 + lane] = acc[1][i];  // P_as
    NP[base + 192 + lane] = acc[3][i];  // P_ts
    NP[base + 256 + lane] = acc[2][i];  // P_td
  }
}

// ---------------------------------------------------------------------------
// Kernel B: bf16-MFMA edge GEMM + fused epilogue, ct-chunked to cap VGPR.
// Wave = 32 edges x 192 cols via mfma_f32_16x16x32_bf16; per ct (16-col tile
// of each of Wa_e/Wt_e/W_ee) only 6 f32x4 accumulators are live.
// P_td gather hoisted to node_final (num is computed WITHOUT the P_td term;
// softmax weights sum to 1 so out_n = num'/denom + P_td + b_T).
// No segment_max: softmax is shift-invariant, logits O(10), exp safe in fp32.
// ---------------------------------------------------------------------------
__global__ __launch_bounds__(256, 5) void edge_pass_mfma(
    const float* __restrict__ e_feat, const int* __restrict__ src,
    const int* __restrict__ dst, const float* __restrict__ W_a,
    const float* __restrict__ W_T, const float* __restrict__ W_ee,
    const float* __restrict__ prelu_a, const float* __restrict__ NP,
    float* __restrict__ denom, float* __restrict__ numer,
    float* __restrict__ out_e) {
  __shared__ short sWT[192 * 64];  // 24 KB, [C][k] bf16, XOR-swizzled
  const int tid = threadIdx.x;
  const int lane = tid & 63;
  const int wid = tid >> 6;

  // Stage W^T -> bf16: elem (C,k) at C*64 + ((k>>3)^(C&7))*8 + (k&7).
  for (int idx = tid; idx < 192 * 32; idx += 256) {
    int C = idx >> 5;
    int k = (idx & 31) * 2;
    float f0, f1;
    if (C < 64)       { f0 = W_a[(128 + k) * 64 + C];        f1 = W_a[(129 + k) * 64 + C]; }
    else if (C < 128) { f0 = W_T[(128 + k) * 64 + (C - 64)]; f1 = W_T[(129 + k) * 64 + (C - 64)]; }
    else              { f0 = W_ee[k * 64 + (C - 128)];       f1 = W_ee[(k + 1) * 64 + (C - 128)]; }
    unsigned pack = ((unsigned)(unsigned short)bf16_rne(f0)) |
                    (((unsigned)(unsigned short)bf16_rne(f1)) << 16);
    int sidx = C * 64 + (((k >> 3) ^ (C & 7)) << 3) + (k & 7);
    *(unsigned*)(&sWT[sidx]) = pack;
  }
  __syncthreads();
  const float pa = prelu_a[0];

  const int row = lane & 15;   // A-row / B-col within 16x16 tile
  const int q   = lane >> 4;   // quarter-wave: k-group / D-row-group

  const int ngroups = N_EDGES / 128;
  for (int g = blockIdx.x; g < ngroups; g += gridDim.x) {
    const int ebase = g * 128 + wid * 32;

    // Per-lane edge endpoints for the 8 edges this lane's quarter owns.
    int es[2][4], ed[2][4];
    #pragma unroll
    for (int rt = 0; rt < 2; ++rt)
      #pragma unroll
      for (int r = 0; r < 4; ++r) {
        int e = ebase + rt * 16 + q * 4 + r;
        es[rt][r] = src[e];
        ed[rt][r] = dst[e];
      }

    // A fragments: lane holds e_feat[ebase+rt*16+row][kt*32 + q*8 + j].
    short8 afrag[2][2];
    #pragma unroll
    for (int rt = 0; rt < 2; ++rt)
      #pragma unroll
      for (int kt = 0; kt < 2; ++kt) {
        const float* p = e_feat + (size_t)(ebase + rt * 16 + row) * 64 + kt * 32 + q * 8;
        float4 v0 = *(const float4*)p;
        float4 v1 = *(const float4*)(p + 4);
        short8 a;
        a[0] = bf16_rne(v0.x); a[1] = bf16_rne(v0.y);
        a[2] = bf16_rne(v0.z); a[3] = bf16_rne(v0.w);
        a[4] = bf16_rne(v1.x); a[5] = bf16_rne(v1.y);
        a[6] = bf16_rne(v1.z); a[7] = bf16_rne(v1.w);
        afrag[rt][kt] = a;
      }

    // ct-chunked GEMM + epilogue: 16 output cols of each matrix at a time.
    #pragma unroll 1
    for (int ct = 0; ct < 4; ++ct) {
      const int c = ct * 16 + row;       // col within 64-wide output
      const int cx = c & 7;              // swizzle key (same for c, 64+c, 128+c)

      f32x4 aa[2], at[2], ae[2];
      #pragma unroll
      for (int rt = 0; rt < 2; ++rt) { aa[rt] = (f32x4){0,0,0,0}; at[rt] = (f32x4){0,0,0,0}; ae[rt] = (f32x4){0,0,0,0}; }

      #pragma unroll
      for (int kt = 0; kt < 2; ++kt) {
        int kg = ((kt * 4 + q) ^ cx) << 3;
        short8 ba = *(const short8*)(&sWT[(c)       * 64 + kg]);
        short8 bt = *(const short8*)(&sWT[(64 + c)  * 64 + kg]);
        short8 be = *(const short8*)(&sWT[(128 + c) * 64 + kg]);
        #pragma unroll
        for (int rt = 0; rt < 2; ++rt) {
          aa[rt] = __builtin_amdgcn_mfma_f32_16x16x32_bf16(afrag[rt][kt], ba, aa[rt], 0, 0, 0);
          at[rt] = __builtin_amdgcn_mfma_f32_16x16x32_bf16(afrag[rt][kt], bt, at[rt], 0, 0, 0);
          ae[rt] = __builtin_amdgcn_mfma_f32_16x16x32_bf16(afrag[rt][kt], be, ae[rt], 0, 0, 0);
        }
      }

      // Epilogue for these 16 cols: D layout col=lane&15, row=(lane>>4)*4+r.
      #pragma unroll
      for (int rt = 0; rt < 2; ++rt) {
        #pragma unroll
        for (int r = 0; r < 4; ++r) {
          int e = ebase + rt * 16 + q * 4 + r;
          int d = ed[rt][r], s = es[rt][r];
          const float* NPd = NP + (size_t)d * 320;
          const float* NPs = NP + (size_t)s * 320;
          float la = NPd[c] + aa[rt][r] + NPs[128 + c];
          float lg = la >= 0.f ? la : pa * la;
          float ex = __expf(lg);
          float un = at[rt][r] + NPs[192 + c];   // P_td part hoisted to node_final
          atomicAdd(denom + (size_t)d * 64 + c, ex);
          atomicAdd(numer + (size_t)d * 64 + c, ex * un);
          out_e[(size_t)e * 64 + c] = NPs[64 + c] + NPd[64 + c] + ae[rt][r];
        }
      }
    }
  }
}

// Kernel C: out_n = denom>0 ? num/denom + P_td + b_T : 0.
__global__ __launch_bounds__(256) void node_final(
    const float* __restrict__ denom, const float* __restrict__ numer,
    const float* __restrict__ NP, const float* __restrict__ b_T,
    float* __restrict__ out_n) {
  int t = blockIdx.x * 256 + threadIdx.x;
  if (t >= N_NODES * 64) return;
  int n = t >> 6, c = t & 63;
  float dn = denom[t];
  out_n[t] = dn > 0.f ? numer[t] / dn + NP[(size_t)n * 320 + 256 + c] + b_T[c] : 0.f;
}

extern "C" void kernel_launch(void* const* d_in, const int* in_sizes, int n_in,
                              void* d_out, int out_size, void* d_ws, size_t ws_size,
                              hipStream_t stream) {
  const float* n_feat  = (const float*)d_in[0];
  const float* e_feat  = (const float*)d_in[1];
  const int*   src     = (const int*)d_in[2];
  const int*   dst     = (const int*)d_in[3];
  const float* W_a     = (const float*)d_in[4];
  const float* W_T     = (const float*)d_in[5];
  const float* b_T     = (const float*)d_in[6];
  const float* W_e     = (const float*)d_in[7];
  const float* W_ee    = (const float*)d_in[8];
  const float* prelu_a = (const float*)d_in[9];

  float* out_n = (float*)d_out;
  float* out_e = out_n + (size_t)N_NODES * 64;

  // ws: NP (50000*320 f32 = 64 MB) | denom (12.8 MB) | numer (12.8 MB)
  float* NP    = (float*)d_ws;
  float* denom = NP + (size_t)N_NODES * 320;
  float* numer = denom + (size_t)N_NODES * 64;

  hipMemsetAsync(denom, 0, (size_t)N_NODES * 64 * 2 * sizeof(float), stream);
  node_proj<<<N_NODES / 16, 64, 0, stream>>>(n_feat, W_a, W_T, W_e, NP);
  edge_pass_mfma<<<2048, 256, 0, stream>>>(e_feat, src, dst, W_a, W_T, W_ee,
                                           prelu_a, NP, denom, numer, out_e);
  node_final<<<(N_NODES * 64 + 255) / 256, 256, 0, stream>>>(denom, numer, NP, b_T, out_n);
}

// Round 4
// 831.549 us; speedup vs baseline: 1.0095x; 1.0095x over previous
//
#include <hip/hip_runtime.h>

#define N_NODES 50000
#define N_EDGES 800000

typedef __attribute__((ext_vector_type(8))) short short8;
typedef __attribute__((ext_vector_type(4))) float f32x4;

// float -> bf16 (round-to-nearest-even), bit pattern in a short.
__device__ __forceinline__ short bf16_rne(float f) {
  unsigned u = __float_as_uint(f);
  unsigned r = (u + 0x7FFFu + ((u >> 16) & 1u)) >> 16;
  return (short)r;
}

// ---------------------------------------------------------------------------
// Kernel A: per-node projections. NP row layout (gather-locality ordered):
//   NP[n][0:64]    = P_ad   (dst window [0,128))
//   NP[n][64:128]  = P_e    (shared by src+dst windows)
//   NP[n][128:192] = P_as   (src window [64,256))
//   NP[n][192:256] = P_ts
//   NP[n][256:320] = P_td   (only read by node_final; hoisted out of edge loop)
// ---------------------------------------------------------------------------
__global__ __launch_bounds__(64) void node_proj(
    const float* __restrict__ n_feat, const float* __restrict__ W_a,
    const float* __restrict__ W_T, const float* __restrict__ W_e,
    float* __restrict__ NP) {
  __shared__ float sN[16 * 128];
  const int lane = threadIdx.x;
  const int n0 = blockIdx.x * 16;

  float4* sN4 = (float4*)sN;
  const float4* nf4 = (const float4*)(n_feat + (size_t)n0 * 128);
  #pragma unroll
  for (int t = 0; t < 8; ++t) sN4[t * 64 + lane] = nf4[t * 64 + lane];
  __syncthreads();

  float acc[5][16];
  #pragma unroll
  for (int qq = 0; qq < 5; ++qq)
    #pragma unroll
    for (int i = 0; i < 16; ++i) acc[qq][i] = 0.f;

  for (int k = 0; k < 128; ++k) {
    float w0 = W_a[k * 64 + lane];          // Wa_d
    float w1 = W_a[(192 + k) * 64 + lane];  // Wa_s
    float w2 = W_T[k * 64 + lane];          // Wt_d
    float w3 = W_T[(192 + k) * 64 + lane];  // Wt_s
    float w4 = W_e[k * 64 + lane];          // W_e
    #pragma unroll
    for (int i = 0; i < 16; ++i) {
      float nv = sN[i * 128 + k];
      acc[0][i] = __builtin_fmaf(nv, w0, acc[0][i]);
      acc[1][i] = __builtin_fmaf(nv, w1, acc[1][i]);
      acc[2][i] = __builtin_fmaf(nv, w2, acc[2][i]);
      acc[3][i] = __builtin_fmaf(nv, w3, acc[3][i]);
      acc[4][i] = __builtin_fmaf(nv, w4, acc[4][i]);
    }
  }
  #pragma unroll
  for (int i = 0; i < 16; ++i) {
    size_t base = (size_t)(n0 + i) * 320;
    NP[base +   0 + lane] = acc[0][i];  // P_ad
    NP[base +  64 + lane] = acc[4][i];  // P_e
    NP[base + 128 + lane] = acc[1][i];  // P_as
    NP[base + 192 + lane] = acc[3][i];  // P_ts
    NP[base + 256 + lane] = acc[2][i];  // P_td
  }
}

// ---------------------------------------------------------------------------
// Kernel B: bf16-MFMA edge GEMM + fused epilogue.
// Wave = 16 edges x 192 cols (12 f32x4 accumulators -> ~90 VGPR, ~5 waves/EU).
// Epilogue is round-2 order: per edge, all 4 col-tiles consecutively, so each
// edge's NP gather windows (contiguous 256-512B) and out_e row (256B) are
// touched back-to-back (round 3's ct-outer chunking doubled HBM traffic).
//   A frag: lane holds e_feat[ebase + (lane&15)][kt*32 + (lane>>4)*8 + j]
//   B frag from LDS W^T [C=192][k=64] bf16, XOR-swizzled (kgroup ^= C&7)
//   D frag: col = lane&15, row(edge) = (lane>>4)*4 + reg   [m89-verified]
// No segment_max: softmax is shift-invariant, logits O(10), exp safe in fp32.
// ---------------------------------------------------------------------------
__global__ __launch_bounds__(256, 5) void edge_pass_mfma(
    const float* __restrict__ e_feat, const int* __restrict__ src,
    const int* __restrict__ dst, const float* __restrict__ W_a,
    const float* __restrict__ W_T, const float* __restrict__ W_ee,
    const float* __restrict__ prelu_a, const float* __restrict__ NP,
    float* __restrict__ denom, float* __restrict__ numer,
    float* __restrict__ out_e) {
  __shared__ short sWT[192 * 64];  // 24 KB, [C][k] bf16, XOR-swizzled
  const int tid = threadIdx.x;
  const int lane = tid & 63;
  const int wid = tid >> 6;

  // Stage W^T -> bf16: elem (C,k) at C*64 + ((k>>3)^(C&7))*8 + (k&7).
  for (int idx = tid; idx < 192 * 32; idx += 256) {
    int C = idx >> 5;
    int k = (idx & 31) * 2;
    float f0, f1;
    if (C < 64)       { f0 = W_a[(128 + k) * 64 + C];        f1 = W_a[(129 + k) * 64 + C]; }
    else if (C < 128) { f0 = W_T[(128 + k) * 64 + (C - 64)]; f1 = W_T[(129 + k) * 64 + (C - 64)]; }
    else              { f0 = W_ee[k * 64 + (C - 128)];       f1 = W_ee[(k + 1) * 64 + (C - 128)]; }
    unsigned pack = ((unsigned)(unsigned short)bf16_rne(f0)) |
                    (((unsigned)(unsigned short)bf16_rne(f1)) << 16);
    int sidx = C * 64 + (((k >> 3) ^ (C & 7)) << 3) + (k & 7);
    *(unsigned*)(&sWT[sidx]) = pack;
  }
  __syncthreads();
  const float pa = prelu_a[0];

  const int row = lane & 15;   // A-row / B-col within 16x16 tile
  const int q   = lane >> 4;   // quarter-wave: k-group / D-row-group

  const int ngroups = N_EDGES / 64;   // 64 edges per block (16 per wave)
  for (int g = blockIdx.x; g < ngroups; g += gridDim.x) {
    const int ebase = g * 64 + wid * 16;

    // src/dst for this quarter's 4 edges: one 16B broadcast load each.
    int4 s4 = *(const int4*)(src + ebase + q * 4);
    int4 d4 = *(const int4*)(dst + ebase + q * 4);

    // A fragments: lane holds e_feat[ebase+row][kt*32 + q*8 + j].
    short8 afrag[2];
    #pragma unroll
    for (int kt = 0; kt < 2; ++kt) {
      const float* p = e_feat + (size_t)(ebase + row) * 64 + kt * 32 + q * 8;
      float4 v0 = *(const float4*)p;
      float4 v1 = *(const float4*)(p + 4);
      short8 a;
      a[0] = bf16_rne(v0.x); a[1] = bf16_rne(v0.y);
      a[2] = bf16_rne(v0.z); a[3] = bf16_rne(v0.w);
      a[4] = bf16_rne(v1.x); a[5] = bf16_rne(v1.y);
      a[6] = bf16_rne(v1.z); a[7] = bf16_rne(v1.w);
      afrag[kt] = a;
    }

    // MFMA: acc[ct] for Wa_e (aa), Wt_e (at), W_ee (ae); ct = 16-col tile.
    f32x4 aa[4], at[4], ae[4];
    #pragma unroll
    for (int ct = 0; ct < 4; ++ct) {
      aa[ct] = (f32x4){0.f, 0.f, 0.f, 0.f};
      at[ct] = (f32x4){0.f, 0.f, 0.f, 0.f};
      ae[ct] = (f32x4){0.f, 0.f, 0.f, 0.f};
    }
    #pragma unroll
    for (int kt = 0; kt < 2; ++kt)
      #pragma unroll
      for (int ct = 0; ct < 4; ++ct) {
        int c = ct * 16 + row;
        int kg = ((kt * 4 + q) ^ (c & 7)) << 3;
        short8 ba = *(const short8*)(&sWT[(c)       * 64 + kg]);
        short8 bt = *(const short8*)(&sWT[(64 + c)  * 64 + kg]);
        short8 be = *(const short8*)(&sWT[(128 + c) * 64 + kg]);
        aa[ct] = __builtin_amdgcn_mfma_f32_16x16x32_bf16(afrag[kt], ba, aa[ct], 0, 0, 0);
        at[ct] = __builtin_amdgcn_mfma_f32_16x16x32_bf16(afrag[kt], bt, at[ct], 0, 0, 0);
        ae[ct] = __builtin_amdgcn_mfma_f32_16x16x32_bf16(afrag[kt], be, ae[ct], 0, 0, 0);
      }

    // Epilogue: per edge (q*4+r), all 4 col-tiles back-to-back.
    #pragma unroll
    for (int r = 0; r < 4; ++r) {
      int e = ebase + q * 4 + r;
      int s = (r == 0) ? s4.x : (r == 1) ? s4.y : (r == 2) ? s4.z : s4.w;
      int d = (r == 0) ? d4.x : (r == 1) ? d4.y : (r == 2) ? d4.z : d4.w;
      const float* NPd = NP + (size_t)d * 320;
      const float* NPs = NP + (size_t)s * 320;
      float* dn = denom + (size_t)d * 64;
      float* nm = numer + (size_t)d * 64;
      float* oe = out_e + (size_t)e * 64;
      #pragma unroll
      for (int ct = 0; ct < 4; ++ct) {
        int c = ct * 16 + row;
        float la = NPd[c] + aa[ct][r] + NPs[128 + c];
        float lg = la >= 0.f ? la : pa * la;
        float ex = __expf(lg);
        float un = at[ct][r] + NPs[192 + c];   // P_td part hoisted to node_final
        atomicAdd(dn + c, ex);
        atomicAdd(nm + c, ex * un);
        oe[c] = NPs[64 + c] + NPd[64 + c] + ae[ct][r];
      }
    }
  }
}

// Kernel C: out_n = denom>0 ? num/denom + P_td + b_T : 0.
__global__ __launch_bounds__(256) void node_final(
    const float* __restrict__ denom, const float* __restrict__ numer,
    const float* __restrict__ NP, const float* __restrict__ b_T,
    float* __restrict__ out_n) {
  int t = blockIdx.x * 256 + threadIdx.x;
  if (t >= N_NODES * 64) return;
  int n = t >> 6, c = t & 63;
  float dn = denom[t];
  out_n[t] = dn > 0.f ? numer[t] / dn + NP[(size_t)n * 320 + 256 + c] + b_T[c] : 0.f;
}

extern "C" void kernel_launch(void* const* d_in, const int* in_sizes, int n_in,
                              void* d_out, int out_size, void* d_ws, size_t ws_size,
                              hipStream_t stream) {
  const float* n_feat  = (const float*)d_in[0];
  const float* e_feat  = (const float*)d_in[1];
  const int*   src     = (const int*)d_in[2];
  const int*   dst     = (const int*)d_in[3];
  const float* W_a     = (const float*)d_in[4];
  const float* W_T     = (const float*)d_in[5];
  const float* b_T     = (const float*)d_in[6];
  const float* W_e     = (const float*)d_in[7];
  const float* W_ee    = (const float*)d_in[8];
  const float* prelu_a = (const float*)d_in[9];

  float* out_n = (float*)d_out;
  float* out_e = out_n + (size_t)N_NODES * 64;

  // ws: NP (50000*320 f32 = 64 MB) | denom (12.8 MB) | numer (12.8 MB)
  float* NP    = (float*)d_ws;
  float* denom = NP + (size_t)N_NODES * 320;
  float* numer = denom + (size_t)N_NODES * 64;

  hipMemsetAsync(denom, 0, (size_t)N_NODES * 64 * 2 * sizeof(float), stream);
  node_proj<<<N_NODES / 16, 64, 0, stream>>>(n_feat, W_a, W_T, W_e, NP);
  edge_pass_mfma<<<2048, 256, 0, stream>>>(e_feat, src, dst, W_a, W_T, W_ee,
                                           prelu_a, NP, denom, numer, out_e);
  node_final<<<(N_NODES * 64 + 255) / 256, 256, 0, stream>>>(denom, numer, NP, b_T, out_n);
}

// Round 5
// 530.947 us; speedup vs baseline: 1.5810x; 1.5662x over previous
//
#include <hip/hip_runtime.h>

#define N_NODES 50000
#define N_EDGES 800000

typedef __attribute__((ext_vector_type(8))) short short8;
typedef __attribute__((ext_vector_type(4))) float f32x4;

// float -> bf16 (round-to-nearest-even), bit pattern in a short.
__device__ __forceinline__ short bf16_rne(float f) {
  unsigned u = __float_as_uint(f);
  unsigned r = (u + 0x7FFFu + ((u >> 16) & 1u)) >> 16;
  return (short)r;
}
__device__ __forceinline__ float bf16_to_f(unsigned short u) {
  return __uint_as_float(((unsigned)u) << 16);
}

// ---------------------------------------------------------------------------
// Kernel A: per-node projections.
// NPb (bf16) row of 256: [0:64)=P_ad | [64:128)=P_e | [128:192)=P_as | [192:256)=P_ts
//   -> dst gather window = cols [0,128) (256B), src window = cols [64,256) (384B)
// Ptd (f32, 50000x64): P_td, only read by node_final (coalesced).
// ---------------------------------------------------------------------------
__global__ __launch_bounds__(64) void node_proj(
    const float* __restrict__ n_feat, const float* __restrict__ W_a,
    const float* __restrict__ W_T, const float* __restrict__ W_e,
    unsigned short* __restrict__ NPb, float* __restrict__ Ptd) {
  __shared__ float sN[16 * 128];
  const int lane = threadIdx.x;
  const int n0 = blockIdx.x * 16;

  float4* sN4 = (float4*)sN;
  const float4* nf4 = (const float4*)(n_feat + (size_t)n0 * 128);
  #pragma unroll
  for (int t = 0; t < 8; ++t) sN4[t * 64 + lane] = nf4[t * 64 + lane];
  __syncthreads();

  float acc[5][16];
  #pragma unroll
  for (int qq = 0; qq < 5; ++qq)
    #pragma unroll
    for (int i = 0; i < 16; ++i) acc[qq][i] = 0.f;

  for (int k = 0; k < 128; ++k) {
    float w0 = W_a[k * 64 + lane];          // Wa_d
    float w1 = W_a[(192 + k) * 64 + lane];  // Wa_s
    float w2 = W_T[k * 64 + lane];          // Wt_d
    float w3 = W_T[(192 + k) * 64 + lane];  // Wt_s
    float w4 = W_e[k * 64 + lane];          // W_e
    #pragma unroll
    for (int i = 0; i < 16; ++i) {
      float nv = sN[i * 128 + k];
      acc[0][i] = __builtin_fmaf(nv, w0, acc[0][i]);
      acc[1][i] = __builtin_fmaf(nv, w1, acc[1][i]);
      acc[2][i] = __builtin_fmaf(nv, w2, acc[2][i]);
      acc[3][i] = __builtin_fmaf(nv, w3, acc[3][i]);
      acc[4][i] = __builtin_fmaf(nv, w4, acc[4][i]);
    }
  }
  #pragma unroll
  for (int i = 0; i < 16; ++i) {
    size_t nb = (size_t)(n0 + i) * 256;
    NPb[nb +   0 + lane] = (unsigned short)bf16_rne(acc[0][i]);  // P_ad
    NPb[nb +  64 + lane] = (unsigned short)bf16_rne(acc[4][i]);  // P_e
    NPb[nb + 128 + lane] = (unsigned short)bf16_rne(acc[1][i]);  // P_as
    NPb[nb + 192 + lane] = (unsigned short)bf16_rne(acc[3][i]);  // P_ts
    Ptd[(size_t)(n0 + i) * 64 + lane] = acc[2][i];               // P_td (f32)
  }
}

// ---------------------------------------------------------------------------
// Kernel B: bf16-MFMA edge GEMM + LDS-transposed round-1-style epilogue.
// Wave = 16 edges x 192 cols. After MFMA, each reg-batch r (4 edges) is dumped
// to a wave-private LDS strip and those 4 edges are processed serially with
// ALL 64 lanes on ONE edge (lane = output col). Every scattered access is a
// single contiguous segment: gathers 128B (bf16), atomics 256B, store 256B —
// vs the D-layout's 4-node x 64B fragmentation of rounds 2-4.
// No segment_max: softmax is shift-invariant, logits O(10), exp safe in fp32.
// ---------------------------------------------------------------------------
__global__ __launch_bounds__(256) void edge_pass_mfma(
    const float* __restrict__ e_feat, const int* __restrict__ src,
    const int* __restrict__ dst, const float* __restrict__ W_a,
    const float* __restrict__ W_T, const float* __restrict__ W_ee,
    const float* __restrict__ prelu_a, const unsigned short* __restrict__ NPb,
    float* __restrict__ denom, float* __restrict__ numer,
    float* __restrict__ out_e) {
  __shared__ short sWT[192 * 64];      // 24 KB, W^T [C][k] bf16, XOR-swizzled
  __shared__ float sAcc[4][4 * 200];   // 12.8 KB: per-wave strip, 4 edges x 192 (+pad)
  const int tid = threadIdx.x;
  const int lane = tid & 63;
  const int wid = tid >> 6;

  // Stage W^T -> bf16: elem (C,k) at C*64 + ((k>>3)^(C&7))*8 + (k&7).
  for (int idx = tid; idx < 192 * 32; idx += 256) {
    int C = idx >> 5;
    int k = (idx & 31) * 2;
    float f0, f1;
    if (C < 64)       { f0 = W_a[(128 + k) * 64 + C];        f1 = W_a[(129 + k) * 64 + C]; }
    else if (C < 128) { f0 = W_T[(128 + k) * 64 + (C - 64)]; f1 = W_T[(129 + k) * 64 + (C - 64)]; }
    else              { f0 = W_ee[k * 64 + (C - 128)];       f1 = W_ee[(k + 1) * 64 + (C - 128)]; }
    unsigned pack = ((unsigned)(unsigned short)bf16_rne(f0)) |
                    (((unsigned)(unsigned short)bf16_rne(f1)) << 16);
    int sidx = C * 64 + (((k >> 3) ^ (C & 7)) << 3) + (k & 7);
    *(unsigned*)(&sWT[sidx]) = pack;
  }
  __syncthreads();
  const float pa = prelu_a[0];

  const int row = lane & 15;   // A-row / B-col within 16x16 tile
  const int q   = lane >> 4;   // quarter-wave: k-group / D-row-group
  float* sA = sAcc[wid];       // wave-private: no __syncthreads needed

  const int ngroups = N_EDGES / 64;   // 64 edges per block (16 per wave)
  for (int g = blockIdx.x; g < ngroups; g += gridDim.x) {
    const int ebase = g * 64 + wid * 16;

    // A fragments: lane holds e_feat[ebase+row][kt*32 + q*8 + j].
    short8 afrag[2];
    #pragma unroll
    for (int kt = 0; kt < 2; ++kt) {
      const float* p = e_feat + (size_t)(ebase + row) * 64 + kt * 32 + q * 8;
      float4 v0 = *(const float4*)p;
      float4 v1 = *(const float4*)(p + 4);
      short8 a;
      a[0] = bf16_rne(v0.x); a[1] = bf16_rne(v0.y);
      a[2] = bf16_rne(v0.z); a[3] = bf16_rne(v0.w);
      a[4] = bf16_rne(v1.x); a[5] = bf16_rne(v1.y);
      a[6] = bf16_rne(v1.z); a[7] = bf16_rne(v1.w);
      afrag[kt] = a;
    }

    // MFMA: aa/at/ae[ct]; D layout col=lane&15, row(edge)=q*4+reg.
    f32x4 aa[4], at[4], ae[4];
    #pragma unroll
    for (int ct = 0; ct < 4; ++ct) {
      aa[ct] = (f32x4){0.f, 0.f, 0.f, 0.f};
      at[ct] = (f32x4){0.f, 0.f, 0.f, 0.f};
      ae[ct] = (f32x4){0.f, 0.f, 0.f, 0.f};
    }
    #pragma unroll
    for (int kt = 0; kt < 2; ++kt)
      #pragma unroll
      for (int ct = 0; ct < 4; ++ct) {
        int c = ct * 16 + row;
        int kg = ((kt * 4 + q) ^ (c & 7)) << 3;
        short8 ba = *(const short8*)(&sWT[(c)       * 64 + kg]);
        short8 bt = *(const short8*)(&sWT[(64 + c)  * 64 + kg]);
        short8 be = *(const short8*)(&sWT[(128 + c) * 64 + kg]);
        aa[ct] = __builtin_amdgcn_mfma_f32_16x16x32_bf16(afrag[kt], ba, aa[ct], 0, 0, 0);
        at[ct] = __builtin_amdgcn_mfma_f32_16x16x32_bf16(afrag[kt], bt, at[ct], 0, 0, 0);
        ae[ct] = __builtin_amdgcn_mfma_f32_16x16x32_bf16(afrag[kt], be, ae[ct], 0, 0, 0);
      }

    // Epilogue in 4 reg-batches: batch r holds edges {ebase + q*4 + r | q}.
    // LDS write (lane q,row -> strip q*200): banks (8q+row)%32, max 2-way = free.
    #pragma unroll
    for (int r = 0; r < 4; ++r) {
      #pragma unroll
      for (int ct = 0; ct < 4; ++ct) {
        sA[q * 200 +       ct * 16 + row] = aa[ct][r];
        sA[q * 200 +  64 + ct * 16 + row] = at[ct][r];
        sA[q * 200 + 128 + ct * 16 + row] = ae[ct][r];
      }
      // 4 edges serially, 64 lanes on one edge (lane = col). LDS reads stride-1.
      #pragma unroll
      for (int j = 0; j < 4; ++j) {
        int e = ebase + j * 4 + r;
        int s = src[e], d = dst[e];  // wave-uniform
        const unsigned short* Pd = NPb + (size_t)d * 256;
        const unsigned short* Ps = NPb + (size_t)s * 256;
        float ad_d = bf16_to_f(Pd[lane]);        // 128B contiguous
        float e_d  = bf16_to_f(Pd[64 + lane]);
        float e_s  = bf16_to_f(Ps[64 + lane]);
        float as_s = bf16_to_f(Ps[128 + lane]);
        float ts_s = bf16_to_f(Ps[192 + lane]);
        float aaE = sA[j * 200 + lane];
        float atE = sA[j * 200 + 64 + lane];
        float aeE = sA[j * 200 + 128 + lane];
        float la = ad_d + aaE + as_s;
        float lg = la >= 0.f ? la : pa * la;
        float ex = __expf(lg);
        float un = atE + ts_s;                   // P_td hoisted to node_final
        atomicAdd(denom + (size_t)d * 64 + lane, ex);       // 256B contiguous
        atomicAdd(numer + (size_t)d * 64 + lane, ex * un);  // 256B contiguous
        out_e[(size_t)e * 64 + lane] = e_s + e_d + aeE;     // 256B contiguous
      }
    }
  }
}

// Kernel C: out_n = denom>0 ? num/denom + P_td + b_T : 0.
__global__ __launch_bounds__(256) void node_final(
    const float* __restrict__ denom, const float* __restrict__ numer,
    const float* __restrict__ Ptd, const float* __restrict__ b_T,
    float* __restrict__ out_n) {
  int t = blockIdx.x * 256 + threadIdx.x;
  if (t >= N_NODES * 64) return;
  float dn = denom[t];
  out_n[t] = dn > 0.f ? numer[t] / dn + Ptd[t] + b_T[t & 63] : 0.f;
}

extern "C" void kernel_launch(void* const* d_in, const int* in_sizes, int n_in,
                              void* d_out, int out_size, void* d_ws, size_t ws_size,
                              hipStream_t stream) {
  const float* n_feat  = (const float*)d_in[0];
  const float* e_feat  = (const float*)d_in[1];
  const int*   src     = (const int*)d_in[2];
  const int*   dst     = (const int*)d_in[3];
  const float* W_a     = (const float*)d_in[4];
  const float* W_T     = (const float*)d_in[5];
  const float* b_T     = (const float*)d_in[6];
  const float* W_e     = (const float*)d_in[7];
  const float* W_ee    = (const float*)d_in[8];
  const float* prelu_a = (const float*)d_in[9];

  float* out_n = (float*)d_out;
  float* out_e = out_n + (size_t)N_NODES * 64;

  // ws: NPb bf16 (50000*256*2B = 25.6MB) | Ptd f32 (12.8MB) | denom | numer
  unsigned short* NPb = (unsigned short*)d_ws;
  float* fbase = (float*)d_ws;
  float* Ptd   = fbase + (size_t)N_NODES * 128;  // after 25.6MB of bf16
  float* denom = Ptd + (size_t)N_NODES * 64;
  float* numer = denom + (size_t)N_NODES * 64;

  hipMemsetAsync(denom, 0, (size_t)N_NODES * 64 * 2 * sizeof(float), stream);
  node_proj<<<N_NODES / 16, 64, 0, stream>>>(n_feat, W_a, W_T, W_e, NPb, Ptd);
  edge_pass_mfma<<<2048, 256, 0, stream>>>(e_feat, src, dst, W_a, W_T, W_ee,
                                           prelu_a, NPb, denom, numer, out_e);
  node_final<<<(N_NODES * 64 + 255) / 256, 256, 0, stream>>>(denom, numer, Ptd, b_T, out_n);
}